// Round 9
// baseline (98.992 us; speedup 1.0000x reference)
//
#include <hip/hip_runtime.h>
#include <math.h>

#define B_    8
#define S_    128
#define K_    12
#define DAR_  256
#define DENC_ 256
#define NNEG_ 128
#define W_    116          // S - K
#define BW_   928          // B * W
#define NIDX_ 118784       // NNEG * W * B

typedef __attribute__((ext_vector_type(8))) short short8;    // 8 bf16
typedef __attribute__((ext_vector_type(4))) float floatx4;   // MFMA C/D
typedef __attribute__((ext_vector_type(4))) unsigned int uintx4;

static __device__ __forceinline__ unsigned short f2bf(float f) {
    union { float f; unsigned int u; } v; v.f = f;
    return (unsigned short)((v.u + 0x7FFFu + ((v.u >> 16) & 1u)) >> 16);  // RNE
}

static __device__ __forceinline__ uintx4 pack2(float4 v0, float4 v1) {
    uintx4 o;
    o.x = f2bf(v0.x) | ((unsigned)f2bf(v0.y) << 16);
    o.y = f2bf(v0.z) | ((unsigned)f2bf(v0.w) << 16);
    o.z = f2bf(v1.x) | ((unsigned)f2bf(v1.y) << 16);
    o.w = f2bf(v1.z) | ((unsigned)f2bf(v1.w) << 16);
    return o;
}

// ---------------------------------------------------------------------------
// K0: cast cFeat/Wp/enc -> bf16 (so the GEMM's tile re-reads move half the
// bytes, warm) and build the gather table. 192 blocks.
// ---------------------------------------------------------------------------
__global__ __launch_bounds__(256) void k0_prep(
    const float* __restrict__ enc, const float* __restrict__ cf,
    const float* __restrict__ wp,
    const int* __restrict__ batchIdx, const int* __restrict__ seqIdx,
    unsigned short* __restrict__ ench, unsigned short* __restrict__ cfh,
    unsigned short* __restrict__ wph, int* __restrict__ idxT)
{
    const int tid0 = blockIdx.x * 256 + threadIdx.x;
    for (int g = tid0; g < 163840; g += 192 * 256) {
        const float* src; unsigned short* dst; int off;
        if (g < 32768)      { src = enc; dst = ench; off = g * 8; }
        else if (g < 65536) { src = cf;  dst = cfh;  off = (g - 32768) * 8; }
        else                { src = wp;  dst = wph;  off = (g - 65536) * 8; }
        float4 v0 = *(const float4*)(src + off);
        float4 v1 = *(const float4*)(src + off + 4);
        uintx4 o = pack2(v0, v1);
        __builtin_nontemporal_store(o, (uintx4*)(dst + off));
    }
    for (int j = tid0; j < NIDX_; j += 192 * 256) {
        const int n = j & 127, bw = j >> 7;
        const int b = bw / W_, w = bw - b * W_;
        const int ii = (b * NNEG_ + n) * W_ + w;
        const int bi = batchIdx[ii];
        int si = seqIdx[ii] + w;               // seqIdx in [1,S), w<=115 -> <243
        if (si >= S_) si -= S_;
        __builtin_nontemporal_store(bi * S_ + si, idxT + j);
    }
}

// ---------------------------------------------------------------------------
// Stage 1: grid (8,4,12), 128(bw) x 64(e) tile. bf16 inputs (K0), so slice
// re-reads are half-width and L3-warm. locCh stores are non-temporal
// (consumed cross-XCD next kernel; keep this kernel's L2 for cfh/wph).
// ---------------------------------------------------------------------------
__global__ __launch_bounds__(256, 2) void stage1_mfma(
    const unsigned short* __restrict__ cfh,   // (B,S,256) bf16
    const unsigned short* __restrict__ wph,   // (K,256,256) bf16
    unsigned short* __restrict__ locCh)       // (K,BW,256) bf16
{
    __shared__ unsigned short Bh[64 * 256];   // 32 KB, swizzled

    const int tid = threadIdx.x;
    const int mt = blockIdx.x;                // 8 tiles of 128 bw rows
    const int nt = blockIdx.y;                // 4 e-tiles of 64
    const int k  = blockIdx.z;

    const int lane = tid & 63, wv = tid >> 6;
    const int l15 = lane & 15, quad = lane >> 4;

    // ---- A fragments: wave handles 2 m-subtiles (32 bw rows) ----
    short8 a[2][8];
#pragma unroll
    for (int im = 0; im < 2; ++im) {
        const int row = mt * 128 + wv * 32 + im * 16 + l15;
        const int rowc = (row < BW_) ? row : (BW_ - 1);       // clamp; masked at store
        const int b = rowc / W_, w = rowc - b * W_;
        const unsigned short* arow = cfh + (size_t)(b * S_ + w) * 256;
#pragma unroll
        for (int kt = 0; kt < 8; ++kt)
            a[im][kt] = *(const short8*)(arow + kt * 32 + quad * 8);
    }

    // ---- B staging: 64 rows x 32 chunks = 2048 uint4, 8/thread ----
#pragma unroll
    for (int i = 0; i < 8; ++i) {
        const int flat = i * 256 + tid;
        const int row = flat >> 5, ch = flat & 31;
        uintx4 bv = *(const uintx4*)(wph + ((size_t)(k * 256 + nt * 64 + row) * 256 + ch * 8));
        *(uintx4*)&Bh[(row * 32 + (ch ^ (row & 7))) * 8] = bv;
    }
    __syncthreads();

    floatx4 acc[2][4];
#pragma unroll
    for (int n4 = 0; n4 < 4; ++n4) {
        const int bn = n4 * 16 + l15;
        short8 bfrag[8];
#pragma unroll
        for (int kt = 0; kt < 8; ++kt) {
            const int ch = kt * 4 + quad;
            bfrag[kt] = *(const short8*)&Bh[(bn * 32 + (ch ^ (bn & 7))) * 8];
        }
#pragma unroll
        for (int im = 0; im < 2; ++im) {
            floatx4 c = (n4 == 0) ? floatx4{0.f, 0.f, 0.f, 0.f} : acc[im][n4];
            c = acc[im][n4];
            c = floatx4{0.f, 0.f, 0.f, 0.f};
#pragma unroll
            for (int kt = 0; kt < 8; ++kt)
                c = __builtin_amdgcn_mfma_f32_16x16x32_bf16(a[im][kt], bfrag[kt], c, 0, 0, 0);
            acc[im][n4] = c;
        }
    }

    // D: col(e)=l15, row(bw)=quad*4+r within subtile; nt scalar stores
#pragma unroll
    for (int im = 0; im < 2; ++im) {
#pragma unroll
        for (int n4 = 0; n4 < 4; ++n4) {
            const int e = nt * 64 + n4 * 16 + l15;
#pragma unroll
            for (int r = 0; r < 4; ++r) {
                const int bwo = mt * 128 + wv * 32 + im * 16 + quad * 4 + r;
                if (bwo < BW_)
                    __builtin_nontemporal_store(f2bf(acc[im][n4][r]),
                        locCh + ((size_t)k * BW_ + bwo) * 256 + e);
            }
        }
    }
}

// ---------------------------------------------------------------------------
// Stage 2: one block per (b,w). Streaming inputs (locCh A-frags, idxT) use
// non-temporal loads so the 512 KB ench gather set stays L2-resident.
// ---------------------------------------------------------------------------
__global__ __launch_bounds__(256, 2) void stage2_mfma(
    const unsigned short* __restrict__ ench,   // (B,S,256) bf16
    const unsigned short* __restrict__ locCh,  // (K,BW,256) bf16
    const int* __restrict__ idxT,              // (BW, 128)
    float* __restrict__ part)                  // (2K, BW)
{
    __shared__ int   idxL[144];
    __shared__ float sc[K_ * 132];   // [0..127]=neg, [128]=pos

    const int tid = threadIdx.x;
    const int bw = blockIdx.x;
    const int b = bw / W_, w = bw - b * W_;

    const int lane = tid & 63, wv = tid >> 6;
    const int l15 = lane & 15, quad = lane >> 4;

    // ---- A fragments: 8 batched nt loads (streaming, read-once) ----
    const int m = (l15 < K_) ? l15 : (K_ - 1);
    const unsigned short* arow = locCh + ((size_t)m * BW_ + bw) * 256;
    short8 a[8];
#pragma unroll
    for (int kt = 0; kt < 8; ++kt)
        a[kt] = __builtin_nontemporal_load((const short8*)(arow + kt * 32 + quad * 8));

    // ---- gather row indices ----
    if (tid < 128)      idxL[tid] = __builtin_nontemporal_load(idxT + bw * 128 + tid);
    else if (tid < 140) idxL[tid] = b * S_ + w + 1 + (tid - 128);   // positives
    else if (tid < 144) idxL[tid] = b * S_ + w;                     // pad
    __syncthreads();

    // ---- batch ALL 24 B-fragment loads (3 tiles/wave x 8 kt), cached ----
    short8 bfr[3][8];
#pragma unroll
    for (int u = 0; u < 3; ++u) {
        const int t = wv + u * 4;              // 0..11, tiles >=9 unused
        const int n = t * 16 + l15;
        const int nn = (t < 9) ? ((n < 140) ? n : 128) : 128;
        const unsigned short* brow = ench + (size_t)idxL[nn] * 256;
#pragma unroll
        for (int kt = 0; kt < 8; ++kt)
            bfr[u][kt] = *(const short8*)(brow + kt * 32 + quad * 8);
    }

    floatx4 accT[3];
#pragma unroll
    for (int u = 0; u < 3; ++u) {
        floatx4 c = {0.f, 0.f, 0.f, 0.f};
#pragma unroll
        for (int kt = 0; kt < 8; ++kt)
            c = __builtin_amdgcn_mfma_f32_16x16x32_bf16(a[kt], bfr[u][kt], c, 0, 0, 0);
        accT[u] = c;
    }

    const float inv = 1.0f / 256.0f;
#pragma unroll
    for (int u = 0; u < 3; ++u) {
        const int t = wv + u * 4;
        if (t < 9) {
#pragma unroll
            for (int r = 0; r < 4; ++r) {
                const int mm = quad * 4 + r;       // accumulator row = k
                if (mm < K_) {
                    const float val = accT[u][r] * inv;
                    if (t < 8)           sc[mm * 132 + t * 16 + l15] = val;  // neg
                    else if (l15 == mm)  sc[mm * 132 + 128] = val;           // pos
                }
            }
        }
    }
    __syncthreads();

    // ---- LSE + acc per k (wave wv: k = wv, wv+4, wv+8) ----
    for (int k = wv; k < K_; k += 4) {
        const float x0  = sc[k * 132 + lane];
        const float x1  = sc[k * 132 + 64 + lane];
        const float pos = sc[k * 132 + 128];
        float mn = fmaxf(x0, x1);
#pragma unroll
        for (int o = 1; o < 64; o <<= 1) mn = fmaxf(mn, __shfl_xor(mn, o, 64));
        const float m2 = fmaxf(mn, pos);
        float s = __expf(x0 - m2) + __expf(x1 - m2);
#pragma unroll
        for (int o = 1; o < 64; o <<= 1) s += __shfl_xor(s, o, 64);
        if (lane == 0) {
            const float lse = m2 + __logf(s + __expf(pos - m2));
            __builtin_nontemporal_store(lse - pos, part + k * BW_ + bw);
            __builtin_nontemporal_store((pos >= mn) ? 1.0f : 0.0f,
                                        part + (K_ + k) * BW_ + bw);
        }
    }
}

// ---------------------------------------------------------------------------
// Stage 3: reduce (2K, BW) partials to the 24 outputs.
// ---------------------------------------------------------------------------
__global__ __launch_bounds__(256) void stage3_reduce(
    const float* __restrict__ part, float* __restrict__ out)
{
    __shared__ float wsum[4];
    const int o = blockIdx.x, tid = threadIdx.x;
    float s = 0.f;
    for (int i = tid; i < BW_; i += 256) s += part[o * BW_ + i];
#pragma unroll
    for (int off = 1; off < 64; off <<= 1) s += __shfl_xor(s, off, 64);
    if ((tid & 63) == 0) wsum[tid >> 6] = s;
    __syncthreads();
    if (tid == 0)
        out[o] = (wsum[0] + wsum[1] + wsum[2] + wsum[3]) / (float)BW_;
}

// ---------------------------------------------------------------------------
extern "C" void kernel_launch(void* const* d_in, const int* in_sizes, int n_in,
                              void* d_out, int out_size, void* d_ws, size_t ws_size,
                              hipStream_t stream) {
    const float* cFeat    = (const float*)d_in[0];
    const float* enc      = (const float*)d_in[1];
    const float* Wp       = (const float*)d_in[2];
    const int*   batchIdx = (const int*)d_in[3];
    const int*   seqIdx   = (const int*)d_in[4];
    float* out = (float*)d_out;

    unsigned short* ench  = (unsigned short*)d_ws;            // 262144 bf16
    unsigned short* cfh   = ench + 262144;                    // 262144 bf16
    unsigned short* wph   = cfh + 262144;                     // 786432 bf16
    unsigned short* locCh = wph + 786432;                     // K*BW*256 bf16
    int*   idxT = (int*)(locCh + (size_t)K_ * BW_ * 256);     // 118784 ints
    float* part = (float*)(idxT + NIDX_);                     // (2K, BW)

    hipLaunchKernelGGL(k0_prep, dim3(192), dim3(256), 0, stream,
                       enc, cFeat, Wp, batchIdx, seqIdx, ench, cfh, wph, idxT);
    hipLaunchKernelGGL(stage1_mfma, dim3(8, 4, 12), dim3(256), 0, stream,
                       cfh, wph, locCh);
    hipLaunchKernelGGL(stage2_mfma, dim3(BW_), dim3(256), 0, stream,
                       ench, locCh, idxT, part);
    hipLaunchKernelGGL(stage3_reduce, dim3(24), dim3(256), 0, stream,
                       part, out);
}